// Round 9
// baseline (120.814 us; speedup 1.0000x reference)
//
#include <hip/hip_runtime.h>
#include <hip/hip_bf16.h>

#define BT   16
#define IH   48
#define IW   48
#define CH   64
#define NH   8
#define HD   8
#define KS   7
#define NPIX (BT*IH*IW)          /* 36864 */
#define QKVC 192
#define LN_EPS 1e-5f
#define QSCALE 0.35355339059327373f

typedef __bf16 bf16_t;
typedef bf16_t bf16x8 __attribute__((ext_vector_type(8)));
typedef float  f32x4  __attribute__((ext_vector_type(4)));
typedef float  f32x2  __attribute__((ext_vector_type(2)));

__device__ __forceinline__ float bflo(unsigned u) { union { unsigned i; float f; } v; v.i = u << 16; return v.f; }
__device__ __forceinline__ float bfhi(unsigned u) { union { unsigned i; float f; } v; v.i = u & 0xffff0000u; return v.f; }
__device__ __forceinline__ f32x2 unp2(unsigned u) { f32x2 r; r.x = bflo(u); r.y = bfhi(u); return r; }

__device__ __forceinline__ bf16x8 pack_bf16x8(float4 lo, float4 hi) {
    bf16x8 r;
    r[0] = (bf16_t)lo.x; r[1] = (bf16_t)lo.y; r[2] = (bf16_t)lo.z; r[3] = (bf16_t)lo.w;
    r[4] = (bf16_t)hi.x; r[5] = (bf16_t)hi.y; r[6] = (bf16_t)hi.z; r[7] = (bf16_t)hi.w;
    return r;
}

// ---------------- K1: QKV projection MFMA GEMM, B-frags register-resident ---
__global__ __launch_bounds__(256) void qkv_kernel(
        const float* __restrict__ x,
        const float* __restrict__ w,
        const float* __restrict__ b,
        __hip_bfloat16* __restrict__ qkv) {
    const int gw   = blockIdx.x * 4 + (threadIdx.x >> 6);  // 0..3455
    const int ngrp = gw % 3;
    const int mg   = gw / 3;             // 0..1151 (2 m-tiles each)
    const int l  = threadIdx.x & 63;
    const int m  = l & 15;
    const int kg = l >> 4;

    const int ch_base = ngrp * 64 + m * 4;
    const float4 bias4 = *(const float4*)(b + ch_base);
    const float scale = (ngrp == 0) ? QSCALE : 1.f;   // q gets 1/sqrt(hd)

    bf16x8 wb0[4], wb1[4];               // held across both m-tiles
    #pragma unroll
    for (int t = 0; t < 4; ++t) {
        const float* wr_ = w + (size_t)(ch_base + t) * CH + kg * 8;
        wb0[t] = pack_bf16x8(*(const float4*)(wr_),      *(const float4*)(wr_ + 4));
        wb1[t] = pack_bf16x8(*(const float4*)(wr_ + 32), *(const float4*)(wr_ + 36));
    }

    #pragma unroll
    for (int mm = 0; mm < 2; ++mm) {
        const int mtile = mg * 2 + mm;
        const float* xr = x + (size_t)(mtile * 16 + m) * CH + kg * 8;
        const bf16x8 a0 = pack_bf16x8(*(const float4*)(xr),      *(const float4*)(xr + 4));
        const bf16x8 a1 = pack_bf16x8(*(const float4*)(xr + 32), *(const float4*)(xr + 36));

        float val[4][4];
        #pragma unroll
        for (int t = 0; t < 4; ++t) {
            f32x4 acc = {0.f, 0.f, 0.f, 0.f};
            acc = __builtin_amdgcn_mfma_f32_16x16x32_bf16(a0, wb0[t], acc, 0, 0, 0);
            acc = __builtin_amdgcn_mfma_f32_16x16x32_bf16(a1, wb1[t], acc, 0, 0, 0);
            const float bias = (t == 0) ? bias4.x : (t == 1) ? bias4.y : (t == 2) ? bias4.z : bias4.w;
            #pragma unroll
            for (int r = 0; r < 4; ++r) val[t][r] = (acc[r] + bias) * scale;
        }
        #pragma unroll
        for (int r = 0; r < 4; ++r) {
            const int pix = mtile * 16 + kg * 4 + r;
            union { ushort4 u; __hip_bfloat16 hh[4]; } pk;
            #pragma unroll
            for (int t = 0; t < 4; ++t) pk.hh[t] = __float2bfloat16(val[t][r]);
            *reinterpret_cast<ushort4*>(qkv + (size_t)pix * QKVC + ch_base) = pk.u;
        }
    }
}

// ---------------- K2: lean attention — no LDS, 64-VGPR target ---------------
// 1 thread = (pixel, head). Full-row MLP batching from L1/L2; f32x2 math to
// bait v_pk_fma_f32; no-max softmax (scores O(1), shift-invariant).
// Block = 4x8 pixel tile x 8 heads = 256 threads. n = blk&15 -> each XCD
// touches 2 images (~1.8 MB qkv) for L2 residency.
__global__ __launch_bounds__(256, 8) void attn_kernel(
        const __hip_bfloat16* __restrict__ qkv,
        const float* __restrict__ rpb,
        __hip_bfloat16* __restrict__ aout) {
    const int blk  = blockIdx.x;         // 0..1151
    const int n    = blk & 15;
    const int tile = blk >> 4;           // 0..71
    const int i0   = (tile / 6) * 4;
    const int j0   = (tile % 6) * 8;
    const int tid  = threadIdx.x;
    const int h    = tid & 7;
    const int pl   = tid >> 3;           // 0..31
    const int i    = i0 + (pl >> 3);
    const int j    = j0 + (pl & 7);
    const size_t img = (size_t)n * (IH * IW);

    f32x2 qv[4];
    {
        const uint4 u = *reinterpret_cast<const uint4*>(
            qkv + (img + i * IW + j) * QKVC + h * HD);
        qv[0] = unp2(u.x); qv[1] = unp2(u.y); qv[2] = unp2(u.z); qv[3] = unp2(u.w);
    }

    int si = i - 3; si = si < 0 ? 0 : (si > IH - KS ? IH - KS : si);
    int sj = j - 3; sj = sj < 0 ? 0 : (sj > IW - KS ? IW - KS : sj);
    const float* rp = rpb + h * (2*KS-1) * (2*KS-1) + (sj - j + (KS - 1));

    float lrun = 0.f;
    f32x2 acc[4];
    #pragma unroll
    for (int d = 0; d < 4; ++d) acc[d] = (f32x2){0.f, 0.f};

    for (int p = 0; p < KS; ++p) {       // 7 neighbor rows
        const int ki = si + p;
        const float* rprow = rp + (ki - i + (KS - 1)) * (2*KS-1);
        const __hip_bfloat16* row = qkv + (img + ki * IW + sj) * QKVC + CH + h * HD;

        uint4 kb[KS];
        float rb[KS];
        #pragma unroll
        for (int qq = 0; qq < KS; ++qq) {
            kb[qq] = *reinterpret_cast<const uint4*>(row + qq * QKVC);
            rb[qq] = rprow[qq];
        }
        float e[KS];
        #pragma unroll
        for (int qq = 0; qq < KS; ++qq) {
            f32x2 s2 = qv[0] * unp2(kb[qq].x);
            s2 += qv[1] * unp2(kb[qq].y);
            s2 += qv[2] * unp2(kb[qq].z);
            s2 += qv[3] * unp2(kb[qq].w);
            e[qq] = __expf(s2.x + s2.y + rb[qq]);    // no-max softmax
        }
        uint4 vb[KS];
        #pragma unroll
        for (int qq = 0; qq < KS; ++qq)
            vb[qq] = *reinterpret_cast<const uint4*>(row + qq * QKVC + CH);
        #pragma unroll
        for (int qq = 0; qq < KS; ++qq) {
            lrun += e[qq];
            acc[0] += e[qq] * unp2(vb[qq].x);
            acc[1] += e[qq] * unp2(vb[qq].y);
            acc[2] += e[qq] * unp2(vb[qq].z);
            acc[3] += e[qq] * unp2(vb[qq].w);
        }
    }
    const float inv = 1.f / lrun;
    union { uint4 u; __hip_bfloat16 hh[8]; } pk;
    #pragma unroll
    for (int d = 0; d < 4; ++d) {
        pk.hh[2*d]   = __float2bfloat16(acc[d].x * inv);
        pk.hh[2*d+1] = __float2bfloat16(acc[d].y * inv);
    }
    *reinterpret_cast<uint4*>(aout + (img + i * IW + j) * CH + h * HD) = pk.u;
}

// ---------------- K3: out-projection MFMA + fused LayerNorm -----------------
// Permuted-B: lane m owns channels m*4..m*4+3 -> float4 stores.
__global__ __launch_bounds__(256) void proj_ln_kernel(
        const __hip_bfloat16* __restrict__ aout,
        const float* __restrict__ pw,
        const float* __restrict__ pb,
        const float* __restrict__ g,
        const float* __restrict__ beta,
        float* __restrict__ out) {
    const int mtile = (blockIdx.x * blockDim.x + threadIdx.x) >> 6;  // 0..2303
    const int l  = threadIdx.x & 63;
    const int m  = l & 15;
    const int kg = l >> 4;

    const __hip_bfloat16* ar = aout + (size_t)(mtile * 16 + m) * CH + kg * 8;
    const bf16x8 a0 = *reinterpret_cast<const bf16x8*>(ar);
    const bf16x8 a1 = *reinterpret_cast<const bf16x8*>(ar + 32);

    const int ch_base = m * 4;
    const float4 bias4 = *(const float4*)(pb + ch_base);

    float val[4][4];                                   // [t][r], ch = m*4+t
    #pragma unroll
    for (int t = 0; t < 4; ++t) {
        const float* wr_ = pw + (size_t)(ch_base + t) * CH + kg * 8;  // permuted B row
        const bf16x8 b0 = pack_bf16x8(*(const float4*)(wr_),      *(const float4*)(wr_ + 4));
        const bf16x8 b1 = pack_bf16x8(*(const float4*)(wr_ + 32), *(const float4*)(wr_ + 36));
        f32x4 acc = {0.f, 0.f, 0.f, 0.f};
        acc = __builtin_amdgcn_mfma_f32_16x16x32_bf16(a0, b0, acc, 0, 0, 0);
        acc = __builtin_amdgcn_mfma_f32_16x16x32_bf16(a1, b1, acc, 0, 0, 0);
        const float bias = (t == 0) ? bias4.x : (t == 1) ? bias4.y : (t == 2) ? bias4.z : bias4.w;
        #pragma unroll
        for (int r = 0; r < 4; ++r) val[t][r] = acc[r] + bias;
    }

    float sm[4];
    #pragma unroll
    for (int r = 0; r < 4; ++r) sm[r] = val[0][r] + val[1][r] + val[2][r] + val[3][r];
    #pragma unroll
    for (int mask = 1; mask <= 8; mask <<= 1) {
        #pragma unroll
        for (int r = 0; r < 4; ++r) sm[r] += __shfl_xor(sm[r], mask, 64);
    }
    float mu[4];
    #pragma unroll
    for (int r = 0; r < 4; ++r) mu[r] = sm[r] * (1.f / 64.f);

    float qs[4];
    #pragma unroll
    for (int r = 0; r < 4; ++r) {
        float a = val[0][r] - mu[r], bq = val[1][r] - mu[r];
        float c = val[2][r] - mu[r], d = val[3][r] - mu[r];
        qs[r] = a * a + bq * bq + c * c + d * d;
    }
    #pragma unroll
    for (int mask = 1; mask <= 8; mask <<= 1) {
        #pragma unroll
        for (int r = 0; r < 4; ++r) qs[r] += __shfl_xor(qs[r], mask, 64);
    }
    float rs[4];
    #pragma unroll
    for (int r = 0; r < 4; ++r) rs[r] = rsqrtf(qs[r] * (1.f / 64.f) + LN_EPS);

    const float4 g4  = *(const float4*)(g + ch_base);
    const float4 be4 = *(const float4*)(beta + ch_base);
    #pragma unroll
    for (int r = 0; r < 4; ++r) {
        const int pix = mtile * 16 + kg * 4 + r;
        float4 o;
        o.x = (val[0][r] - mu[r]) * rs[r] * g4.x + be4.x;
        o.y = (val[1][r] - mu[r]) * rs[r] * g4.y + be4.y;
        o.z = (val[2][r] - mu[r]) * rs[r] * g4.z + be4.z;
        o.w = (val[3][r] - mu[r]) * rs[r] * g4.w + be4.w;
        *reinterpret_cast<float4*>(out + (size_t)pix * CH + ch_base) = o;
    }
}

extern "C" void kernel_launch(void* const* d_in, const int* in_sizes, int n_in,
                              void* d_out, int out_size, void* d_ws, size_t ws_size,
                              hipStream_t stream) {
    const float* x      = (const float*)d_in[0];
    const float* qkv_w  = (const float*)d_in[1];
    const float* qkv_b  = (const float*)d_in[2];
    const float* proj_w = (const float*)d_in[3];
    const float* proj_b = (const float*)d_in[4];
    const float* rpb    = (const float*)d_in[5];
    const float* ln_g   = (const float*)d_in[6];
    const float* ln_b   = (const float*)d_in[7];
    float* out = (float*)d_out;

    // ws: [qkv bf16: NPIX*192*2 = 14,155,776 B][aout bf16: NPIX*64*2 = 4,718,592 B]
    __hip_bfloat16* qkv  = (__hip_bfloat16*)d_ws;
    __hip_bfloat16* aout = (__hip_bfloat16*)((char*)d_ws + (size_t)NPIX * QKVC * 2);

    qkv_kernel<<<864, 256, 0, stream>>>(x, qkv_w, qkv_b, qkv);
    attn_kernel<<<1152, 256, 0, stream>>>(qkv, rpb, aout);
    proj_ln_kernel<<<576, 256, 0, stream>>>(aout, proj_w, proj_b, ln_g, ln_b, out);
}

// Round 10
// 115.819 us; speedup vs baseline: 1.0431x; 1.0431x over previous
//
#include <hip/hip_runtime.h>
#include <hip/hip_bf16.h>

#define BT   16
#define IH   48
#define IW   48
#define CH   64
#define NH   8
#define HD   8
#define KS   7
#define NPIX (BT*IH*IW)          /* 36864 */
#define QKVC 192
#define LN_EPS 1e-5f
#define QSCALE 0.35355339059327373f

#define TSH  4                   /* tile rows */
#define TSW  8                   /* tile cols */
#define TP   (TSH*TSW)           /* 32 tile pixels */
#define AOS  72                  /* attn-out LDS row stride bf16 (144B) */

typedef __bf16 bf16_t;
typedef bf16_t bf16x8 __attribute__((ext_vector_type(8)));
typedef float  f32x4  __attribute__((ext_vector_type(4)));
typedef float  f32x2  __attribute__((ext_vector_type(2)));

__device__ __forceinline__ float bflo(unsigned u) { union { unsigned i; float f; } v; v.i = u << 16; return v.f; }
__device__ __forceinline__ float bfhi(unsigned u) { union { unsigned i; float f; } v; v.i = u & 0xffff0000u; return v.f; }
__device__ __forceinline__ f32x2 unp2(unsigned u) { f32x2 r; r.x = bflo(u); r.y = bfhi(u); return r; }

__device__ __forceinline__ bf16x8 pack_bf16x8(float4 lo, float4 hi) {
    bf16x8 r;
    r[0] = (bf16_t)lo.x; r[1] = (bf16_t)lo.y; r[2] = (bf16_t)lo.z; r[3] = (bf16_t)lo.w;
    r[4] = (bf16_t)hi.x; r[5] = (bf16_t)hi.y; r[6] = (bf16_t)hi.z; r[7] = (bf16_t)hi.w;
    return r;
}

// ---------------- K1: QKV projection MFMA GEMM, B-frags register-resident ---
__global__ __launch_bounds__(256) void qkv_kernel(
        const float* __restrict__ x,
        const float* __restrict__ w,
        const float* __restrict__ b,
        __hip_bfloat16* __restrict__ qkv) {
    const int gw   = blockIdx.x * 4 + (threadIdx.x >> 6);  // 0..3455
    const int ngrp = gw % 3;
    const int mg   = gw / 3;             // 0..1151 (2 m-tiles each)
    const int l  = threadIdx.x & 63;
    const int m  = l & 15;
    const int kg = l >> 4;

    const int ch_base = ngrp * 64 + m * 4;
    const float4 bias4 = *(const float4*)(b + ch_base);
    const float scale = (ngrp == 0) ? QSCALE : 1.f;   // q gets 1/sqrt(hd)

    bf16x8 wb0[4], wb1[4];               // held across both m-tiles
    #pragma unroll
    for (int t = 0; t < 4; ++t) {
        const float* wr_ = w + (size_t)(ch_base + t) * CH + kg * 8;
        wb0[t] = pack_bf16x8(*(const float4*)(wr_),      *(const float4*)(wr_ + 4));
        wb1[t] = pack_bf16x8(*(const float4*)(wr_ + 32), *(const float4*)(wr_ + 36));
    }

    #pragma unroll
    for (int mm = 0; mm < 2; ++mm) {
        const int mtile = mg * 2 + mm;
        const float* xr = x + (size_t)(mtile * 16 + m) * CH + kg * 8;
        const bf16x8 a0 = pack_bf16x8(*(const float4*)(xr),      *(const float4*)(xr + 4));
        const bf16x8 a1 = pack_bf16x8(*(const float4*)(xr + 32), *(const float4*)(xr + 36));

        float val[4][4];
        #pragma unroll
        for (int t = 0; t < 4; ++t) {
            f32x4 acc = {0.f, 0.f, 0.f, 0.f};
            acc = __builtin_amdgcn_mfma_f32_16x16x32_bf16(a0, wb0[t], acc, 0, 0, 0);
            acc = __builtin_amdgcn_mfma_f32_16x16x32_bf16(a1, wb1[t], acc, 0, 0, 0);
            const float bias = (t == 0) ? bias4.x : (t == 1) ? bias4.y : (t == 2) ? bias4.z : bias4.w;
            #pragma unroll
            for (int r = 0; r < 4; ++r) val[t][r] = (acc[r] + bias) * scale;
        }
        #pragma unroll
        for (int r = 0; r < 4; ++r) {
            const int pix = mtile * 16 + kg * 4 + r;
            union { ushort4 u; __hip_bfloat16 hh[4]; } pk;
            #pragma unroll
            for (int t = 0; t < 4; ++t) pk.hh[t] = __float2bfloat16(val[t][r]);
            *reinterpret_cast<ushort4*>(qkv + (size_t)pix * QKVC + ch_base) = pk.u;
        }
    }
}

// ---------------- K2: lean attention (global reads) + proj + LN -------------
// Block = 4x8 pixel tile x 8 heads = 256 threads; only LDS is the 4.6 KB
// attn-out hand-off. Attention reads k/v straight from L1/L2 with full-row
// MLP batching; no-max softmax (scores O(1), shift-invariant). n = blk&15
// keeps each XCD on 2 images (~1.8 MB qkv, L2-resident).
__global__ __launch_bounds__(256, 4) void attn_proj_ln_kernel(
        const __hip_bfloat16* __restrict__ qkv,
        const float* __restrict__ rpb,
        const float* __restrict__ pw,
        const float* __restrict__ pb,
        const float* __restrict__ g,
        const float* __restrict__ beta,
        float* __restrict__ out) {
    __shared__ __align__(16) __hip_bfloat16 ao[TP * AOS];   // 4,608 B

    const int blk  = blockIdx.x;         // 0..1151
    const int n    = blk & 15;
    const int tile = blk >> 4;           // 0..71
    const int i0   = (tile / 6) * TSH;
    const int j0   = (tile % 6) * TSW;
    const int tid  = threadIdx.x;
    const size_t img = (size_t)n * (IH * IW);

    // ---- phase 1: attention, 1 thread = (pixel, head) ----
    {
        const int h  = tid & 7;
        const int pl = tid >> 3;             // 0..31
        const int i  = i0 + (pl >> 3);
        const int j  = j0 + (pl & 7);

        f32x2 qv[4];
        {
            const uint4 u = *reinterpret_cast<const uint4*>(
                qkv + (img + i * IW + j) * QKVC + h * HD);
            qv[0] = unp2(u.x); qv[1] = unp2(u.y); qv[2] = unp2(u.z); qv[3] = unp2(u.w);
        }

        int si = i - 3; si = si < 0 ? 0 : (si > IH - KS ? IH - KS : si);
        int sj = j - 3; sj = sj < 0 ? 0 : (sj > IW - KS ? IW - KS : sj);
        const float* rp = rpb + h * (2*KS-1) * (2*KS-1) + (sj - j + (KS - 1));

        float lrun = 0.f;
        f32x2 acc[4];
        #pragma unroll
        for (int d = 0; d < 4; ++d) acc[d] = (f32x2){0.f, 0.f};

        for (int p = 0; p < KS; ++p) {       // 7 neighbor rows
            const int ki = si + p;
            const float* rprow = rp + (ki - i + (KS - 1)) * (2*KS-1);
            const __hip_bfloat16* row = qkv + (img + ki * IW + sj) * QKVC + CH + h * HD;

            uint4 kb[KS];
            float rb[KS];
            #pragma unroll
            for (int qq = 0; qq < KS; ++qq) {
                kb[qq] = *reinterpret_cast<const uint4*>(row + qq * QKVC);
                rb[qq] = rprow[qq];
            }
            float e[KS];
            #pragma unroll
            for (int qq = 0; qq < KS; ++qq) {
                f32x2 s2 = qv[0] * unp2(kb[qq].x);
                s2 += qv[1] * unp2(kb[qq].y);
                s2 += qv[2] * unp2(kb[qq].z);
                s2 += qv[3] * unp2(kb[qq].w);
                e[qq] = __expf(s2.x + s2.y + rb[qq]);    // no-max softmax
            }
            uint4 vb[KS];
            #pragma unroll
            for (int qq = 0; qq < KS; ++qq)
                vb[qq] = *reinterpret_cast<const uint4*>(row + qq * QKVC + CH);
            #pragma unroll
            for (int qq = 0; qq < KS; ++qq) {
                lrun += e[qq];
                acc[0] += e[qq] * unp2(vb[qq].x);
                acc[1] += e[qq] * unp2(vb[qq].y);
                acc[2] += e[qq] * unp2(vb[qq].z);
                acc[3] += e[qq] * unp2(vb[qq].w);
            }
        }
        const float inv = 1.f / lrun;
        union { uint4 u; __hip_bfloat16 hh[8]; } pk;
        #pragma unroll
        for (int d = 0; d < 4; ++d) {
            pk.hh[2*d]   = __float2bfloat16(acc[d].x * inv);
            pk.hh[2*d+1] = __float2bfloat16(acc[d].y * inv);
        }
        *reinterpret_cast<uint4*>(ao + pl * AOS + h * HD) = pk.u;
    }
    __syncthreads();

    // ---- phase 2: proj + LN, waves 0-1 (2 m-tiles of 16 pixels) ----
    const int wv = tid >> 6;
    if (wv < 2) {
        const int l  = tid & 63;
        const int m  = l & 15;
        const int kg = l >> 4;

        const __hip_bfloat16* ar = ao + (wv * 16 + m) * AOS + kg * 8;
        const bf16x8 a0 = *reinterpret_cast<const bf16x8*>(ar);
        const bf16x8 a1 = *reinterpret_cast<const bf16x8*>(ar + 32);

        const int ch_base = m * 4;
        const float4 bias4 = *(const float4*)(pb + ch_base);

        float val[4][4];                                   // [t][r], ch = m*4+t
        #pragma unroll
        for (int t = 0; t < 4; ++t) {
            const float* wr_ = pw + (size_t)(ch_base + t) * CH + kg * 8;  // permuted B row
            const bf16x8 b0 = pack_bf16x8(*(const float4*)(wr_),      *(const float4*)(wr_ + 4));
            const bf16x8 b1 = pack_bf16x8(*(const float4*)(wr_ + 32), *(const float4*)(wr_ + 36));
            f32x4 acc = {0.f, 0.f, 0.f, 0.f};
            acc = __builtin_amdgcn_mfma_f32_16x16x32_bf16(a0, b0, acc, 0, 0, 0);
            acc = __builtin_amdgcn_mfma_f32_16x16x32_bf16(a1, b1, acc, 0, 0, 0);
            const float bias = (t == 0) ? bias4.x : (t == 1) ? bias4.y : (t == 2) ? bias4.z : bias4.w;
            #pragma unroll
            for (int r = 0; r < 4; ++r) val[t][r] = acc[r] + bias;
        }

        float sm[4];
        #pragma unroll
        for (int r = 0; r < 4; ++r) sm[r] = val[0][r] + val[1][r] + val[2][r] + val[3][r];
        #pragma unroll
        for (int mask = 1; mask <= 8; mask <<= 1) {
            #pragma unroll
            for (int r = 0; r < 4; ++r) sm[r] += __shfl_xor(sm[r], mask, 64);
        }
        float mu[4];
        #pragma unroll
        for (int r = 0; r < 4; ++r) mu[r] = sm[r] * (1.f / 64.f);

        float qs[4];
        #pragma unroll
        for (int r = 0; r < 4; ++r) {
            float a = val[0][r] - mu[r], bq = val[1][r] - mu[r];
            float c = val[2][r] - mu[r], d = val[3][r] - mu[r];
            qs[r] = a * a + bq * bq + c * c + d * d;
        }
        #pragma unroll
        for (int mask = 1; mask <= 8; mask <<= 1) {
            #pragma unroll
            for (int r = 0; r < 4; ++r) qs[r] += __shfl_xor(qs[r], mask, 64);
        }
        float rs[4];
        #pragma unroll
        for (int r = 0; r < 4; ++r) rs[r] = rsqrtf(qs[r] * (1.f / 64.f) + LN_EPS);

        const float4 g4  = *(const float4*)(g + ch_base);
        const float4 be4 = *(const float4*)(beta + ch_base);
        #pragma unroll
        for (int r = 0; r < 4; ++r) {
            const int pl = wv * 16 + kg * 4 + r;          // local pixel
            const int gi = i0 + (pl >> 3), gj = j0 + (pl & 7);
            float4 o;
            o.x = (val[0][r] - mu[r]) * rs[r] * g4.x + be4.x;
            o.y = (val[1][r] - mu[r]) * rs[r] * g4.y + be4.y;
            o.z = (val[2][r] - mu[r]) * rs[r] * g4.z + be4.z;
            o.w = (val[3][r] - mu[r]) * rs[r] * g4.w + be4.w;
            *reinterpret_cast<float4*>(out + (img + gi * IW + gj) * CH + ch_base) = o;
        }
    }
}

extern "C" void kernel_launch(void* const* d_in, const int* in_sizes, int n_in,
                              void* d_out, int out_size, void* d_ws, size_t ws_size,
                              hipStream_t stream) {
    const float* x      = (const float*)d_in[0];
    const float* qkv_w  = (const float*)d_in[1];
    const float* qkv_b  = (const float*)d_in[2];
    const float* proj_w = (const float*)d_in[3];
    const float* proj_b = (const float*)d_in[4];
    const float* rpb    = (const float*)d_in[5];
    const float* ln_g   = (const float*)d_in[6];
    const float* ln_b   = (const float*)d_in[7];
    float* out = (float*)d_out;

    // ws: [qkv bf16: NPIX*192*2 = 14,155,776 B]
    __hip_bfloat16* qkv = (__hip_bfloat16*)d_ws;

    qkv_kernel<<<864, 256, 0, stream>>>(x, qkv_w, qkv_b, qkv);
    attn_proj_ln_kernel<<<1152, 256, 0, stream>>>(qkv, rpb, proj_w, proj_b,
                                                  ln_g, ln_b, out);
}

// Round 11
// 115.672 us; speedup vs baseline: 1.0445x; 1.0013x over previous
//
#include <hip/hip_runtime.h>
#include <hip/hip_bf16.h>

#define BT   16
#define IH   48
#define IW   48
#define CH   64
#define NH   8
#define HD   8
#define KS   7
#define NPIX (BT*IH*IW)          /* 36864 */
#define QKVC 192
#define LN_EPS 1e-5f
#define QSCALE 0.35355339059327373f

#define TSH  4                   /* tile rows */
#define TSW  8                   /* tile cols */
#define TP   (TSH*TSW)           /* 32 tile pixels */
#define AOS  72                  /* attn-out LDS row stride bf16 (144B) */

typedef __bf16 bf16_t;
typedef bf16_t bf16x8 __attribute__((ext_vector_type(8)));
typedef float  f32x4  __attribute__((ext_vector_type(4)));
typedef float  f32x2  __attribute__((ext_vector_type(2)));

__device__ __forceinline__ float bflo(unsigned u) { union { unsigned i; float f; } v; v.i = u << 16; return v.f; }
__device__ __forceinline__ float bfhi(unsigned u) { union { unsigned i; float f; } v; v.i = u & 0xffff0000u; return v.f; }
__device__ __forceinline__ f32x2 unp2(unsigned u) { f32x2 r; r.x = bflo(u); r.y = bfhi(u); return r; }

// unaligned (4-B) float4 load — compiler emits global_load_dwordx4 (unaligned ok on gfx950)
__device__ __forceinline__ float4 ldf4u(const float* p) {
    float4 r; __builtin_memcpy(&r, p, 16); return r;
}

__device__ __forceinline__ bf16x8 pack_bf16x8(float4 lo, float4 hi) {
    bf16x8 r;
    r[0] = (bf16_t)lo.x; r[1] = (bf16_t)lo.y; r[2] = (bf16_t)lo.z; r[3] = (bf16_t)lo.w;
    r[4] = (bf16_t)hi.x; r[5] = (bf16_t)hi.y; r[6] = (bf16_t)hi.z; r[7] = (bf16_t)hi.w;
    return r;
}

// ---------------- K1: QKV projection MFMA GEMM, B-frags register-resident ---
__global__ __launch_bounds__(256) void qkv_kernel(
        const float* __restrict__ x,
        const float* __restrict__ w,
        const float* __restrict__ b,
        __hip_bfloat16* __restrict__ qkv) {
    const int gw   = blockIdx.x * 4 + (threadIdx.x >> 6);  // 0..3455
    const int ngrp = gw % 3;
    const int mg   = gw / 3;             // 0..1151 (2 m-tiles each)
    const int l  = threadIdx.x & 63;
    const int m  = l & 15;
    const int kg = l >> 4;

    const int ch_base = ngrp * 64 + m * 4;
    const float4 bias4 = *(const float4*)(b + ch_base);
    const float scale = (ngrp == 0) ? QSCALE : 1.f;   // q gets 1/sqrt(hd)

    bf16x8 wb0[4], wb1[4];               // held across both m-tiles
    #pragma unroll
    for (int t = 0; t < 4; ++t) {
        const float* wr_ = w + (size_t)(ch_base + t) * CH + kg * 8;
        wb0[t] = pack_bf16x8(*(const float4*)(wr_),      *(const float4*)(wr_ + 4));
        wb1[t] = pack_bf16x8(*(const float4*)(wr_ + 32), *(const float4*)(wr_ + 36));
    }

    #pragma unroll
    for (int mm = 0; mm < 2; ++mm) {
        const int mtile = mg * 2 + mm;
        const float* xr = x + (size_t)(mtile * 16 + m) * CH + kg * 8;
        const bf16x8 a0 = pack_bf16x8(*(const float4*)(xr),      *(const float4*)(xr + 4));
        const bf16x8 a1 = pack_bf16x8(*(const float4*)(xr + 32), *(const float4*)(xr + 36));

        float val[4][4];
        #pragma unroll
        for (int t = 0; t < 4; ++t) {
            f32x4 acc = {0.f, 0.f, 0.f, 0.f};
            acc = __builtin_amdgcn_mfma_f32_16x16x32_bf16(a0, wb0[t], acc, 0, 0, 0);
            acc = __builtin_amdgcn_mfma_f32_16x16x32_bf16(a1, wb1[t], acc, 0, 0, 0);
            const float bias = (t == 0) ? bias4.x : (t == 1) ? bias4.y : (t == 2) ? bias4.z : bias4.w;
            #pragma unroll
            for (int r = 0; r < 4; ++r) val[t][r] = (acc[r] + bias) * scale;
        }
        #pragma unroll
        for (int r = 0; r < 4; ++r) {
            const int pix = mtile * 16 + kg * 4 + r;
            union { ushort4 u; __hip_bfloat16 hh[4]; } pk;
            #pragma unroll
            for (int t = 0; t < 4; ++t) pk.hh[t] = __float2bfloat16(val[t][r]);
            *reinterpret_cast<ushort4*>(qkv + (size_t)pix * QKVC + ch_base) = pk.u;
        }
    }
}

// ---------------- K2: paired-pixel attention + proj + LN --------------------
// Thread = (vertical pixel PAIR, head): pixels (i,j),(i+1,j) share sj and 6-7
// window rows -> one 8x7 row-col union of k/v loads serves both pixels
// (~2x fewer gather instructions). All pair masks are wave-uniform.
// Block = 4x8 tile = 16 pairs x 8 heads = 128 threads; 1152 blocks.
__global__ __launch_bounds__(128) void attn_proj_ln_kernel(
        const __hip_bfloat16* __restrict__ qkv,
        const float* __restrict__ rpb,
        const float* __restrict__ pw,
        const float* __restrict__ pb,
        const float* __restrict__ g,
        const float* __restrict__ beta,
        float* __restrict__ out) {
    __shared__ __align__(16) __hip_bfloat16 ao[TP * AOS];   // 4,608 B

    const int blk  = blockIdx.x;         // 0..1151
    const int n    = blk & 15;           // image -> XCD = n%8 (L2 locality)
    const int tile = blk >> 4;           // 0..71
    const int i0   = (tile / 6) * TSH;
    const int j0   = (tile % 6) * TSW;
    const int tid  = threadIdx.x;
    const size_t img = (size_t)n * (IH * IW);

    // ---- phase 1: attention ----
    {
        const int h  = tid & 7;
        const int pr = tid >> 3;             // 0..15 pair index
        const int pi = pr >> 3;              // 0..1  (wave-uniform: wave = pi)
        const int pj = pr & 7;
        const int i  = i0 + pi * 2;          // wave-uniform
        const int j  = j0 + pj;
        const int pl0 = pi * 16 + pj;        // local pixel of (i,j)
        const int pl1 = pl0 + 8;             // local pixel of (i+1,j)

        f32x2 q0[4], q1[4];
        {
            const uint4 u = *reinterpret_cast<const uint4*>(
                qkv + (img + i * IW + j) * QKVC + h * HD);
            q0[0] = unp2(u.x); q0[1] = unp2(u.y); q0[2] = unp2(u.z); q0[3] = unp2(u.w);
            const uint4 v = *reinterpret_cast<const uint4*>(
                qkv + (img + (i + 1) * IW + j) * QKVC + h * HD);
            q1[0] = unp2(v.x); q1[1] = unp2(v.y); q1[2] = unp2(v.z); q1[3] = unp2(v.w);
        }

        int si0 = i - 3;     si0 = si0 < 0 ? 0 : (si0 > IH - KS ? IH - KS : si0);
        int si1 = i - 2;     si1 = si1 < 0 ? 0 : (si1 > IH - KS ? IH - KS : si1);
        int sj  = j - 3;     sj  = sj  < 0 ? 0 : (sj  > IW - KS ? IW - KS : sj);
        const int off    = si1 - si0;        // 0 or 1, wave-uniform
        const int rbase0 = si0 - i + 6;      // 1..6
        const float* rpc = rpb + h * (2*KS-1) * (2*KS-1) + (sj - j + (KS - 1));

        float lr0 = 0.f, lr1 = 0.f;
        f32x2 a0[4], a1[4];
        #pragma unroll
        for (int d = 0; d < 4; ++d) { a0[d] = (f32x2){0.f,0.f}; a1[d] = (f32x2){0.f,0.f}; }

        for (int p = 0; p < 8; ++p) {        // union of both pixels' window rows
            if (p == 7 && off == 0) break;   // uniform: 8th row unused
            const bool d0 = (p < 7);                   // px0 active rows
            const bool d1 = (p > 0) || (off == 0);     // px1 active rows
            const __hip_bfloat16* row =
                qkv + (img + (si0 + p) * IW + sj) * QKVC + CH + h * HD;

            uint4 kb[KS], vb[KS];
            #pragma unroll
            for (int qq = 0; qq < KS; ++qq) {
                kb[qq] = *reinterpret_cast<const uint4*>(row + qq * QKVC);
                vb[qq] = *reinterpret_cast<const uint4*>(row + qq * QKVC + CH);
            }
            float4 r0a = {0,0,0,0}, r0b = {0,0,0,0}, r1a = {0,0,0,0}, r1b = {0,0,0,0};
            if (d0) {
                const float* rr = rpc + (rbase0 + p) * (2*KS-1);
                r0a = ldf4u(rr); r0b = ldf4u(rr + 3);
            }
            if (d1) {
                const float* rr = rpc + (rbase0 - 1 + p) * (2*KS-1);
                r1a = ldf4u(rr); r1b = ldf4u(rr + 3);
            }

            float s0[KS], s1[KS];
            #pragma unroll
            for (int qq = 0; qq < KS; ++qq) {
                const f32x2 k0 = unp2(kb[qq].x), k1 = unp2(kb[qq].y);
                const f32x2 k2 = unp2(kb[qq].z), k3 = unp2(kb[qq].w);
                f32x2 t0 = q0[0]*k0 + q0[1]*k1 + q0[2]*k2 + q0[3]*k3;
                f32x2 t1 = q1[0]*k0 + q1[1]*k1 + q1[2]*k2 + q1[3]*k3;
                s0[qq] = t0.x + t0.y;
                s1[qq] = t1.x + t1.y;
            }
            float e0[KS], e1[KS];
            #pragma unroll
            for (int qq = 0; qq < KS; ++qq) { e0[qq] = 0.f; e1[qq] = 0.f; }
            if (d0) {
                e0[0] = __expf(s0[0] + r0a.x); e0[1] = __expf(s0[1] + r0a.y);
                e0[2] = __expf(s0[2] + r0a.z); e0[3] = __expf(s0[3] + r0a.w);
                e0[4] = __expf(s0[4] + r0b.y); e0[5] = __expf(s0[5] + r0b.z);
                e0[6] = __expf(s0[6] + r0b.w);
            }
            if (d1) {
                e1[0] = __expf(s1[0] + r1a.x); e1[1] = __expf(s1[1] + r1a.y);
                e1[2] = __expf(s1[2] + r1a.z); e1[3] = __expf(s1[3] + r1a.w);
                e1[4] = __expf(s1[4] + r1b.y); e1[5] = __expf(s1[5] + r1b.z);
                e1[6] = __expf(s1[6] + r1b.w);
            }
            #pragma unroll
            for (int qq = 0; qq < KS; ++qq) {
                const f32x2 v0 = unp2(vb[qq].x), v1 = unp2(vb[qq].y);
                const f32x2 v2 = unp2(vb[qq].z), v3 = unp2(vb[qq].w);
                lr0 += e0[qq];
                a0[0] += e0[qq] * v0; a0[1] += e0[qq] * v1;
                a0[2] += e0[qq] * v2; a0[3] += e0[qq] * v3;
                lr1 += e1[qq];
                a1[0] += e1[qq] * v0; a1[1] += e1[qq] * v1;
                a1[2] += e1[qq] * v2; a1[3] += e1[qq] * v3;
            }
        }
        const float inv0 = 1.f / lr0;
        const float inv1 = 1.f / lr1;
        union { uint4 u; __hip_bfloat16 hh[8]; } pk;
        #pragma unroll
        for (int d = 0; d < 4; ++d) {
            pk.hh[2*d]   = __float2bfloat16(a0[d].x * inv0);
            pk.hh[2*d+1] = __float2bfloat16(a0[d].y * inv0);
        }
        *reinterpret_cast<uint4*>(ao + pl0 * AOS + h * HD) = pk.u;
        #pragma unroll
        for (int d = 0; d < 4; ++d) {
            pk.hh[2*d]   = __float2bfloat16(a1[d].x * inv1);
            pk.hh[2*d+1] = __float2bfloat16(a1[d].y * inv1);
        }
        *reinterpret_cast<uint4*>(ao + pl1 * AOS + h * HD) = pk.u;
    }
    __syncthreads();

    // ---- phase 2: proj + LN, both waves (2 m-tiles of 16 pixels) ----
    {
        const int wv = tid >> 6;             // 0..1
        const int l  = tid & 63;
        const int m  = l & 15;
        const int kg = l >> 4;

        const __hip_bfloat16* ar = ao + (wv * 16 + m) * AOS + kg * 8;
        const bf16x8 a0 = *reinterpret_cast<const bf16x8*>(ar);
        const bf16x8 a1 = *reinterpret_cast<const bf16x8*>(ar + 32);

        const int ch_base = m * 4;
        const float4 bias4 = *(const float4*)(pb + ch_base);

        float val[4][4];                                   // [t][r], ch = m*4+t
        #pragma unroll
        for (int t = 0; t < 4; ++t) {
            const float* wr_ = pw + (size_t)(ch_base + t) * CH + kg * 8;  // permuted B row
            const bf16x8 b0 = pack_bf16x8(*(const float4*)(wr_),      *(const float4*)(wr_ + 4));
            const bf16x8 b1 = pack_bf16x8(*(const float4*)(wr_ + 32), *(const float4*)(wr_ + 36));
            f32x4 acc = {0.f, 0.f, 0.f, 0.f};
            acc = __builtin_amdgcn_mfma_f32_16x16x32_bf16(a0, b0, acc, 0, 0, 0);
            acc = __builtin_amdgcn_mfma_f32_16x16x32_bf16(a1, b1, acc, 0, 0, 0);
            const float bias = (t == 0) ? bias4.x : (t == 1) ? bias4.y : (t == 2) ? bias4.z : bias4.w;
            #pragma unroll
            for (int r = 0; r < 4; ++r) val[t][r] = acc[r] + bias;
        }

        float sm[4];
        #pragma unroll
        for (int r = 0; r < 4; ++r) sm[r] = val[0][r] + val[1][r] + val[2][r] + val[3][r];
        #pragma unroll
        for (int mask = 1; mask <= 8; mask <<= 1) {
            #pragma unroll
            for (int r = 0; r < 4; ++r) sm[r] += __shfl_xor(sm[r], mask, 64);
        }
        float mu[4];
        #pragma unroll
        for (int r = 0; r < 4; ++r) mu[r] = sm[r] * (1.f / 64.f);

        float qs[4];
        #pragma unroll
        for (int r = 0; r < 4; ++r) {
            float a = val[0][r] - mu[r], bq = val[1][r] - mu[r];
            float c = val[2][r] - mu[r], d = val[3][r] - mu[r];
            qs[r] = a * a + bq * bq + c * c + d * d;
        }
        #pragma unroll
        for (int mask = 1; mask <= 8; mask <<= 1) {
            #pragma unroll
            for (int r = 0; r < 4; ++r) qs[r] += __shfl_xor(qs[r], mask, 64);
        }
        float rs[4];
        #pragma unroll
        for (int r = 0; r < 4; ++r) rs[r] = rsqrtf(qs[r] * (1.f / 64.f) + LN_EPS);

        const float4 g4  = *(const float4*)(g + ch_base);
        const float4 be4 = *(const float4*)(beta + ch_base);
        #pragma unroll
        for (int r = 0; r < 4; ++r) {
            const int pl = wv * 16 + kg * 4 + r;          // local pixel
            const int gi = i0 + (pl >> 3), gj = j0 + (pl & 7);
            float4 o;
            o.x = (val[0][r] - mu[r]) * rs[r] * g4.x + be4.x;
            o.y = (val[1][r] - mu[r]) * rs[r] * g4.y + be4.y;
            o.z = (val[2][r] - mu[r]) * rs[r] * g4.z + be4.z;
            o.w = (val[3][r] - mu[r]) * rs[r] * g4.w + be4.w;
            *reinterpret_cast<float4*>(out + (img + gi * IW + gj) * CH + ch_base) = o;
        }
    }
}

extern "C" void kernel_launch(void* const* d_in, const int* in_sizes, int n_in,
                              void* d_out, int out_size, void* d_ws, size_t ws_size,
                              hipStream_t stream) {
    const float* x      = (const float*)d_in[0];
    const float* qkv_w  = (const float*)d_in[1];
    const float* qkv_b  = (const float*)d_in[2];
    const float* proj_w = (const float*)d_in[3];
    const float* proj_b = (const float*)d_in[4];
    const float* rpb    = (const float*)d_in[5];
    const float* ln_g   = (const float*)d_in[6];
    const float* ln_b   = (const float*)d_in[7];
    float* out = (float*)d_out;

    // ws: [qkv bf16: NPIX*192*2 = 14,155,776 B]
    __hip_bfloat16* qkv = (__hip_bfloat16*)d_ws;

    qkv_kernel<<<864, 256, 0, stream>>>(x, qkv_w, qkv_b, qkv);
    attn_proj_ln_kernel<<<1152, 128, 0, stream>>>(qkv, rpb, proj_w, proj_b,
                                                  ln_g, ln_b, out);
}

// Round 12
// 113.102 us; speedup vs baseline: 1.0682x; 1.0227x over previous
//
#include <hip/hip_runtime.h>
#include <hip/hip_bf16.h>

#define BT   16
#define IH   48
#define IW   48
#define CH   64
#define NH   8
#define HD   8
#define KS   7
#define NPIX (BT*IH*IW)          /* 36864 */
#define QKVC 192
#define LN_EPS 1e-5f
#define QSCALE 0.35355339059327373f

#define TSH  4                   /* tile rows */
#define TSW  8                   /* tile cols */
#define TP   (TSH*TSW)           /* 32 tile pixels */
#define AOS  72                  /* attn-out LDS row stride bf16 (144B) */

typedef __bf16 bf16_t;
typedef bf16_t bf16x8 __attribute__((ext_vector_type(8)));
typedef float  f32x4  __attribute__((ext_vector_type(4)));
typedef float  f32x2  __attribute__((ext_vector_type(2)));

__device__ __forceinline__ float bflo(unsigned u) { union { unsigned i; float f; } v; v.i = u << 16; return v.f; }
__device__ __forceinline__ float bfhi(unsigned u) { union { unsigned i; float f; } v; v.i = u & 0xffff0000u; return v.f; }
__device__ __forceinline__ f32x2 unp2(unsigned u) { f32x2 r; r.x = bflo(u); r.y = bfhi(u); return r; }

// unaligned (4-B) float4 load — compiler emits global_load_dwordx4
__device__ __forceinline__ float4 ldf4u(const float* p) {
    float4 r; __builtin_memcpy(&r, p, 16); return r;
}

__device__ __forceinline__ bf16x8 pack_bf16x8(float4 lo, float4 hi) {
    bf16x8 r;
    r[0] = (bf16_t)lo.x; r[1] = (bf16_t)lo.y; r[2] = (bf16_t)lo.z; r[3] = (bf16_t)lo.w;
    r[4] = (bf16_t)hi.x; r[5] = (bf16_t)hi.y; r[6] = (bf16_t)hi.z; r[7] = (bf16_t)hi.w;
    return r;
}

// ---------------- K1: QKV projection MFMA GEMM ------------------------------
// Block = 192 threads = 3 waves; wave wv = ngrp (q/k/v group); all 3 waves
// share the SAME two m-tiles -> x fetched once from HBM, 2x from L1 (was 3x
// from HBM/IF when ngrp-waves lived in different blocks). B-frags register-
// resident; permuted-B epilogue: lane m owns 4 consecutive channels.
__global__ __launch_bounds__(192) void qkv_kernel(
        const float* __restrict__ x,
        const float* __restrict__ w,
        const float* __restrict__ b,
        __hip_bfloat16* __restrict__ qkv) {
    const int mg   = blockIdx.x;         // 0..1151 (2 m-tiles each)
    const int ngrp = threadIdx.x >> 6;   // 0..2 (wave = group)
    const int l  = threadIdx.x & 63;
    const int m  = l & 15;
    const int kg = l >> 4;

    const int ch_base = ngrp * 64 + m * 4;
    const float4 bias4 = *(const float4*)(b + ch_base);
    const float scale = (ngrp == 0) ? QSCALE : 1.f;   // q gets 1/sqrt(hd)

    bf16x8 wb0[4], wb1[4];               // held across both m-tiles
    #pragma unroll
    for (int t = 0; t < 4; ++t) {
        const float* wr_ = w + (size_t)(ch_base + t) * CH + kg * 8;
        wb0[t] = pack_bf16x8(*(const float4*)(wr_),      *(const float4*)(wr_ + 4));
        wb1[t] = pack_bf16x8(*(const float4*)(wr_ + 32), *(const float4*)(wr_ + 36));
    }

    #pragma unroll
    for (int mm = 0; mm < 2; ++mm) {
        const int mtile = mg * 2 + mm;
        const float* xr = x + (size_t)(mtile * 16 + m) * CH + kg * 8;
        const bf16x8 a0 = pack_bf16x8(*(const float4*)(xr),      *(const float4*)(xr + 4));
        const bf16x8 a1 = pack_bf16x8(*(const float4*)(xr + 32), *(const float4*)(xr + 36));

        float val[4][4];
        #pragma unroll
        for (int t = 0; t < 4; ++t) {
            f32x4 acc = {0.f, 0.f, 0.f, 0.f};
            acc = __builtin_amdgcn_mfma_f32_16x16x32_bf16(a0, wb0[t], acc, 0, 0, 0);
            acc = __builtin_amdgcn_mfma_f32_16x16x32_bf16(a1, wb1[t], acc, 0, 0, 0);
            const float bias = (t == 0) ? bias4.x : (t == 1) ? bias4.y : (t == 2) ? bias4.z : bias4.w;
            #pragma unroll
            for (int r = 0; r < 4; ++r) val[t][r] = (acc[r] + bias) * scale;
        }
        #pragma unroll
        for (int r = 0; r < 4; ++r) {
            const int pix = mtile * 16 + kg * 4 + r;
            union { ushort4 u; __hip_bfloat16 hh[4]; } pk;
            #pragma unroll
            for (int t = 0; t < 4; ++t) pk.hh[t] = __float2bfloat16(val[t][r]);
            *reinterpret_cast<ushort4*>(qkv + (size_t)pix * QKVC + ch_base) = pk.u;
        }
    }
}

// ---------------- K2: paired-pixel attention + proj + LN (unchanged r11) ----
__global__ __launch_bounds__(128) void attn_proj_ln_kernel(
        const __hip_bfloat16* __restrict__ qkv,
        const float* __restrict__ rpb,
        const float* __restrict__ pw,
        const float* __restrict__ pb,
        const float* __restrict__ g,
        const float* __restrict__ beta,
        float* __restrict__ out) {
    __shared__ __align__(16) __hip_bfloat16 ao[TP * AOS];   // 4,608 B

    const int blk  = blockIdx.x;         // 0..1151
    const int n    = blk & 15;           // image -> XCD = n%8 (L2 locality)
    const int tile = blk >> 4;           // 0..71
    const int i0   = (tile / 6) * TSH;
    const int j0   = (tile % 6) * TSW;
    const int tid  = threadIdx.x;
    const size_t img = (size_t)n * (IH * IW);

    // ---- phase 1: attention ----
    {
        const int h  = tid & 7;
        const int pr = tid >> 3;             // 0..15 pair index
        const int pi = pr >> 3;              // 0..1  (wave-uniform)
        const int pj = pr & 7;
        const int i  = i0 + pi * 2;
        const int j  = j0 + pj;
        const int pl0 = pi * 16 + pj;
        const int pl1 = pl0 + 8;

        f32x2 q0[4], q1[4];
        {
            const uint4 u = *reinterpret_cast<const uint4*>(
                qkv + (img + i * IW + j) * QKVC + h * HD);
            q0[0] = unp2(u.x); q0[1] = unp2(u.y); q0[2] = unp2(u.z); q0[3] = unp2(u.w);
            const uint4 v = *reinterpret_cast<const uint4*>(
                qkv + (img + (i + 1) * IW + j) * QKVC + h * HD);
            q1[0] = unp2(v.x); q1[1] = unp2(v.y); q1[2] = unp2(v.z); q1[3] = unp2(v.w);
        }

        int si0 = i - 3;     si0 = si0 < 0 ? 0 : (si0 > IH - KS ? IH - KS : si0);
        int si1 = i - 2;     si1 = si1 < 0 ? 0 : (si1 > IH - KS ? IH - KS : si1);
        int sj  = j - 3;     sj  = sj  < 0 ? 0 : (sj  > IW - KS ? IW - KS : sj);
        const int off    = si1 - si0;        // 0 or 1, wave-uniform
        const int rbase0 = si0 - i + 6;      // 1..6
        const float* rpc = rpb + h * (2*KS-1) * (2*KS-1) + (sj - j + (KS - 1));

        float lr0 = 0.f, lr1 = 0.f;
        f32x2 a0[4], a1[4];
        #pragma unroll
        for (int d = 0; d < 4; ++d) { a0[d] = (f32x2){0.f,0.f}; a1[d] = (f32x2){0.f,0.f}; }

        for (int p = 0; p < 8; ++p) {        // union of both pixels' window rows
            if (p == 7 && off == 0) break;   // uniform: 8th row unused
            const bool d0 = (p < 7);
            const bool d1 = (p > 0) || (off == 0);
            const __hip_bfloat16* row =
                qkv + (img + (si0 + p) * IW + sj) * QKVC + CH + h * HD;

            uint4 kb[KS], vb[KS];
            #pragma unroll
            for (int qq = 0; qq < KS; ++qq) {
                kb[qq] = *reinterpret_cast<const uint4*>(row + qq * QKVC);
                vb[qq] = *reinterpret_cast<const uint4*>(row + qq * QKVC + CH);
            }
            float4 r0a = {0,0,0,0}, r0b = {0,0,0,0}, r1a = {0,0,0,0}, r1b = {0,0,0,0};
            if (d0) {
                const float* rr = rpc + (rbase0 + p) * (2*KS-1);
                r0a = ldf4u(rr); r0b = ldf4u(rr + 3);
            }
            if (d1) {
                const float* rr = rpc + (rbase0 - 1 + p) * (2*KS-1);
                r1a = ldf4u(rr); r1b = ldf4u(rr + 3);
            }

            float s0[KS], s1[KS];
            #pragma unroll
            for (int qq = 0; qq < KS; ++qq) {
                const f32x2 k0 = unp2(kb[qq].x), k1 = unp2(kb[qq].y);
                const f32x2 k2 = unp2(kb[qq].z), k3 = unp2(kb[qq].w);
                f32x2 t0 = q0[0]*k0 + q0[1]*k1 + q0[2]*k2 + q0[3]*k3;
                f32x2 t1 = q1[0]*k0 + q1[1]*k1 + q1[2]*k2 + q1[3]*k3;
                s0[qq] = t0.x + t0.y;
                s1[qq] = t1.x + t1.y;
            }
            float e0[KS], e1[KS];
            #pragma unroll
            for (int qq = 0; qq < KS; ++qq) { e0[qq] = 0.f; e1[qq] = 0.f; }
            if (d0) {
                e0[0] = __expf(s0[0] + r0a.x); e0[1] = __expf(s0[1] + r0a.y);
                e0[2] = __expf(s0[2] + r0a.z); e0[3] = __expf(s0[3] + r0a.w);
                e0[4] = __expf(s0[4] + r0b.y); e0[5] = __expf(s0[5] + r0b.z);
                e0[6] = __expf(s0[6] + r0b.w);
            }
            if (d1) {
                e1[0] = __expf(s1[0] + r1a.x); e1[1] = __expf(s1[1] + r1a.y);
                e1[2] = __expf(s1[2] + r1a.z); e1[3] = __expf(s1[3] + r1a.w);
                e1[4] = __expf(s1[4] + r1b.y); e1[5] = __expf(s1[5] + r1b.z);
                e1[6] = __expf(s1[6] + r1b.w);
            }
            #pragma unroll
            for (int qq = 0; qq < KS; ++qq) {
                const f32x2 v0 = unp2(vb[qq].x), v1 = unp2(vb[qq].y);
                const f32x2 v2 = unp2(vb[qq].z), v3 = unp2(vb[qq].w);
                lr0 += e0[qq];
                a0[0] += e0[qq] * v0; a0[1] += e0[qq] * v1;
                a0[2] += e0[qq] * v2; a0[3] += e0[qq] * v3;
                lr1 += e1[qq];
                a1[0] += e1[qq] * v0; a1[1] += e1[qq] * v1;
                a1[2] += e1[qq] * v2; a1[3] += e1[qq] * v3;
            }
        }
        const float inv0 = 1.f / lr0;
        const float inv1 = 1.f / lr1;
        union { uint4 u; __hip_bfloat16 hh[8]; } pk;
        #pragma unroll
        for (int d = 0; d < 4; ++d) {
            pk.hh[2*d]   = __float2bfloat16(a0[d].x * inv0);
            pk.hh[2*d+1] = __float2bfloat16(a0[d].y * inv0);
        }
        *reinterpret_cast<uint4*>(ao + pl0 * AOS + h * HD) = pk.u;
        #pragma unroll
        for (int d = 0; d < 4; ++d) {
            pk.hh[2*d]   = __float2bfloat16(a1[d].x * inv1);
            pk.hh[2*d+1] = __float2bfloat16(a1[d].y * inv1);
        }
        *reinterpret_cast<uint4*>(ao + pl1 * AOS + h * HD) = pk.u;
    }
    __syncthreads();

    // ---- phase 2: proj + LN, both waves (2 m-tiles of 16 pixels) ----
    {
        const int wv = tid >> 6;             // 0..1
        const int l  = tid & 63;
        const int m  = l & 15;
        const int kg = l >> 4;

        const __hip_bfloat16* ar = ao + (wv * 16 + m) * AOS + kg * 8;
        const bf16x8 a0 = *reinterpret_cast<const bf16x8*>(ar);
        const bf16x8 a1 = *reinterpret_cast<const bf16x8*>(ar + 32);

        const int ch_base = m * 4;
        const float4 bias4 = *(const float4*)(pb + ch_base);

        float val[4][4];                                   // [t][r], ch = m*4+t
        #pragma unroll
        for (int t = 0; t < 4; ++t) {
            const float* wr_ = pw + (size_t)(ch_base + t) * CH + kg * 8;  // permuted B row
            const bf16x8 b0 = pack_bf16x8(*(const float4*)(wr_),      *(const float4*)(wr_ + 4));
            const bf16x8 b1 = pack_bf16x8(*(const float4*)(wr_ + 32), *(const float4*)(wr_ + 36));
            f32x4 acc = {0.f, 0.f, 0.f, 0.f};
            acc = __builtin_amdgcn_mfma_f32_16x16x32_bf16(a0, b0, acc, 0, 0, 0);
            acc = __builtin_amdgcn_mfma_f32_16x16x32_bf16(a1, b1, acc, 0, 0, 0);
            const float bias = (t == 0) ? bias4.x : (t == 1) ? bias4.y : (t == 2) ? bias4.z : bias4.w;
            #pragma unroll
            for (int r = 0; r < 4; ++r) val[t][r] = acc[r] + bias;
        }

        float sm[4];
        #pragma unroll
        for (int r = 0; r < 4; ++r) sm[r] = val[0][r] + val[1][r] + val[2][r] + val[3][r];
        #pragma unroll
        for (int mask = 1; mask <= 8; mask <<= 1) {
            #pragma unroll
            for (int r = 0; r < 4; ++r) sm[r] += __shfl_xor(sm[r], mask, 64);
        }
        float mu[4];
        #pragma unroll
        for (int r = 0; r < 4; ++r) mu[r] = sm[r] * (1.f / 64.f);

        float qs[4];
        #pragma unroll
        for (int r = 0; r < 4; ++r) {
            float a = val[0][r] - mu[r], bq = val[1][r] - mu[r];
            float c = val[2][r] - mu[r], d = val[3][r] - mu[r];
            qs[r] = a * a + bq * bq + c * c + d * d;
        }
        #pragma unroll
        for (int mask = 1; mask <= 8; mask <<= 1) {
            #pragma unroll
            for (int r = 0; r < 4; ++r) qs[r] += __shfl_xor(qs[r], mask, 64);
        }
        float rs[4];
        #pragma unroll
        for (int r = 0; r < 4; ++r) rs[r] = rsqrtf(qs[r] * (1.f / 64.f) + LN_EPS);

        const float4 g4  = *(const float4*)(g + ch_base);
        const float4 be4 = *(const float4*)(beta + ch_base);
        #pragma unroll
        for (int r = 0; r < 4; ++r) {
            const int pl = wv * 16 + kg * 4 + r;          // local pixel
            const int gi = i0 + (pl >> 3), gj = j0 + (pl & 7);
            float4 o;
            o.x = (val[0][r] - mu[r]) * rs[r] * g4.x + be4.x;
            o.y = (val[1][r] - mu[r]) * rs[r] * g4.y + be4.y;
            o.z = (val[2][r] - mu[r]) * rs[r] * g4.z + be4.z;
            o.w = (val[3][r] - mu[r]) * rs[r] * g4.w + be4.w;
            *reinterpret_cast<float4*>(out + (img + gi * IW + gj) * CH + ch_base) = o;
        }
    }
}

extern "C" void kernel_launch(void* const* d_in, const int* in_sizes, int n_in,
                              void* d_out, int out_size, void* d_ws, size_t ws_size,
                              hipStream_t stream) {
    const float* x      = (const float*)d_in[0];
    const float* qkv_w  = (const float*)d_in[1];
    const float* qkv_b  = (const float*)d_in[2];
    const float* proj_w = (const float*)d_in[3];
    const float* proj_b = (const float*)d_in[4];
    const float* rpb    = (const float*)d_in[5];
    const float* ln_g   = (const float*)d_in[6];
    const float* ln_b   = (const float*)d_in[7];
    float* out = (float*)d_out;

    // ws: [qkv bf16: NPIX*192*2 = 14,155,776 B]
    __hip_bfloat16* qkv = (__hip_bfloat16*)d_ws;

    qkv_kernel<<<1152, 192, 0, stream>>>(x, qkv_w, qkv_b, qkv);   // 3 waves/block share x
    attn_proj_ln_kernel<<<1152, 128, 0, stream>>>(qkv, rpb, proj_w, proj_b,
                                                  ln_g, ln_b, out);
}